// Round 1
// 348.596 us; speedup vs baseline: 1.0116x; 1.0116x over previous
//
#include <hip/hip_runtime.h>
#include <hip/hip_bf16.h>

typedef __attribute__((ext_vector_type(8))) short short8;
typedef __attribute__((ext_vector_type(4))) float float4v;
typedef __attribute__((ext_vector_type(4))) unsigned int uint4v;

#define DDIM 1024

__device__ __forceinline__ unsigned short f2bf(float f) {
  unsigned u = __builtin_bit_cast(unsigned, f);
  unsigned r = (u + 0x7fffu + ((u >> 16) & 1u)) >> 16;   // RNE
  return (unsigned short)r;
}
__device__ __forceinline__ unsigned pk2(float lo, float hi) {
  return (unsigned)f2bf(lo) | ((unsigned)f2bf(hi) << 16);
}
__device__ __forceinline__ void cvt8(const float* src, unsigned short* dst) {
  float4v a = *(const float4v*)(src);
  float4v b = *(const float4v*)(src + 4);
  uint4v pk;
  pk.x = pk2(a.x, a.y); pk.y = pk2(a.z, a.w);
  pk.z = pk2(b.x, b.y); pk.w = pk2(b.z, b.w);
  *(uint4v*)dst = pk;
}

// ---- prepass: W (1M) + eth (32M) fp32 -> bf16 in workspace ----
__global__ __launch_bounds__(256) void convert_all(const float* __restrict__ W,
                                                   const float* __restrict__ eth,
                                                   unsigned short* __restrict__ Wb,
                                                   unsigned short* __restrict__ ethB) {
  int b = blockIdx.x;
  if (b < 512) {
    size_t i = ((size_t)b * 256 + threadIdx.x) * 8;
    cvt8(W + i, Wb + i);
  } else {
    size_t i = ((size_t)(b - 512) * 256 + threadIdx.x) * 8;
    cvt8(eth + i, ethB + i);
  }
}
__global__ __launch_bounds__(256) void convert_w(const float* __restrict__ W,
                                                 unsigned short* __restrict__ Wb) {
  size_t i = ((size_t)blockIdx.x * 256 + threadIdx.x) * 8;
  cvt8(W + i, Wb + i);
}

// ---- main: 128 rows x 128 d-cols per block, K=1024, depth-2 counted-vmcnt pipe ----
// grid 2048 = 256 m-groups x 8 d-tiles; d-tile = bid&7 pins each XCD to one
// 256 KB W slice (L2-resident). LDS 33 KB -> 4 blocks/CU (16 waves).
// K-loop: raw s_barrier + counted s_waitcnt vmcnt(4) -- tile k+1's DMAs stay in
// flight across the whole iter (T3/T4); no vmcnt(0) drain in the loop body.
__global__ __launch_bounds__(256, 4) void bilinear_bf16(const float* __restrict__ elg,
                                                        const unsigned short* __restrict__ ethB,
                                                        const unsigned short* __restrict__ Wb,
                                                        float* __restrict__ out) {
  __shared__ unsigned short Wbuf[2][128 * 32];  // 16 KB
  __shared__ unsigned short ethL[2][128 * 32];  // 16 KB
  __shared__ float wsum[4][64];                 // 1 KB

  const int tid  = threadIdx.x;
  const int lane = tid & 63;
  const int w    = tid >> 6;
  const int quad = lane >> 4;
  const int l15  = lane & 15;
  const int rowhalf = w >> 1;       // wave's 64-row half
  const int colhalf = w & 1;        // wave's 64-col half
  const int m0   = (blockIdx.x >> 3) * 128;
  const int d0   = (blockIdx.x & 7) * 128;
  const int wr = lane >> 2, wu = lane & 3;   // DMA row/unit role

  // stage K-chunk ek into buffer buf: 4 DMA instrs/thread, 16 KB total
  auto stage = [&](int ek, int buf) {
    const int e0 = ek * 32;
#pragma unroll
    for (int j = 0; j < 2; ++j) {
      const int R0 = w * 16 + j * 64;        // 16-row slab per wave-instr
      const int r  = R0 + wr;
      const int ug = wu ^ ((r >> 1) & 3);    // swizzle on the GLOBAL side
      const unsigned short* gw = Wb   + (size_t)(d0 + r) * DDIM + e0 + ug * 8;
      const unsigned short* ge = ethB + (size_t)(m0 + r) * DDIM + e0 + ug * 8;
      unsigned short* lw = &Wbuf[buf][R0 * 32 + lane * 8];
      unsigned short* le = &ethL[buf][R0 * 32 + lane * 8];
      __builtin_amdgcn_global_load_lds(
          (const __attribute__((address_space(1))) unsigned int*)gw,
          (__attribute__((address_space(3))) unsigned int*)lw, 16, 0, 0);
      __builtin_amdgcn_global_load_lds(
          (const __attribute__((address_space(1))) unsigned int*)ge,
          (__attribute__((address_space(3))) unsigned int*)le, 16, 0, 0);
    }
  };

  float4v acc[4][4];
#pragma unroll
  for (int ct = 0; ct < 4; ++ct)
#pragma unroll
    for (int rt = 0; rt < 4; ++rt)
      acc[ct][rt] = (float4v){0.f, 0.f, 0.f, 0.f};

  // depth-2 prologue: tiles 0 and 1 in flight (8 DMAs/thread outstanding)
  stage(0, 0);
  stage(1, 1);

  for (int ek = 0; ek < 32; ++ek) {
    const int cur = ek & 1;
    // tile ek's 4 DMAs are the oldest outstanding; leave tile ek+1's in flight
    if (ek < 31) asm volatile("s_waitcnt vmcnt(4)" ::: "memory");
    else         asm volatile("s_waitcnt vmcnt(0)" ::: "memory");
    __builtin_amdgcn_s_barrier();            // all waves: buf[cur] fully landed

    short8 aF[4], bF[4];
#pragma unroll
    for (int rt = 0; rt < 4; ++rt) {         // A[m=l15][k=quad*8+j]
      int r  = rowhalf * 64 + rt * 16 + l15;
      int pu = quad ^ ((r >> 1) & 3);
      aF[rt] = *(const short8*)&ethL[cur][r * 32 + pu * 8];
    }
#pragma unroll
    for (int ct = 0; ct < 4; ++ct) {         // B[k][n=l15] = W row d
      int r  = colhalf * 64 + ct * 16 + l15;
      int pu = quad ^ ((r >> 1) & 3);
      bF[ct] = *(const short8*)&Wbuf[cur][r * 32 + pu * 8];
    }
    asm volatile("s_waitcnt lgkmcnt(0)" ::: "memory");  // my reads of buf[cur] retired
    __builtin_amdgcn_s_barrier();            // all waves' reads retired -> cur free
    if (ek < 30) stage(ek + 2, cur);         // refill cur; overlaps MFMA + next wait

    __builtin_amdgcn_s_setprio(1);
#pragma unroll
    for (int ct = 0; ct < 4; ++ct)
#pragma unroll
      for (int rt = 0; rt < 4; ++rt)
        acc[ct][rt] = __builtin_amdgcn_mfma_f32_16x16x32_bf16(aF[rt], bF[ct], acc[ct][rt], 0, 0, 0);
    __builtin_amdgcn_s_setprio(0);
  }

  // fused epilogue: p[m] = sum_col elg[m][col] * u[m][col] over this d-tile
  float p[16];
#pragma unroll
  for (int j = 0; j < 16; ++j) p[j] = 0.f;
#pragma unroll
  for (int ct = 0; ct < 4; ++ct) {
    int col = d0 + colhalf * 64 + ct * 16 + l15;
#pragma unroll
    for (int rt = 0; rt < 4; ++rt) {
      const float* ep = elg + (size_t)(m0 + rowhalf * 64 + rt * 16 + quad * 4) * DDIM + col;
#pragma unroll
      for (int i = 0; i < 4; ++i)
        p[rt * 4 + i] += acc[ct][rt][i] * ep[(size_t)i * DDIM];
    }
  }
#pragma unroll
  for (int off = 1; off < 16; off <<= 1)     // sum the 16 col-lanes per row
#pragma unroll
    for (int j = 0; j < 16; ++j)
      p[j] += __shfl_xor(p[j], off);
  if (l15 == 0) {
#pragma unroll
    for (int rt = 0; rt < 4; ++rt)
#pragma unroll
      for (int i = 0; i < 4; ++i)
        wsum[w][rt * 16 + quad * 4 + i] = p[rt * 4 + i];   // local row in half
  }
  __syncthreads();
  if (tid < 128) {
    int local = tid & 63, half = tid >> 6;
    float s = wsum[half * 2][local] + wsum[half * 2 + 1][local];
    atomicAdd(&out[m0 + tid], s);            // 8 d-tile blocks per output
  }
}

// ---- fallback (ws too small for eth_bf16): round-2 proven kernel ----
#define ETH_STRIDE 40
__global__ __launch_bounds__(256, 3) void bilinear_fp32eth(const float* __restrict__ elg,
                                                           const float* __restrict__ eth,
                                                           const unsigned short* __restrict__ Wb,
                                                           float* __restrict__ out) {
  __shared__ unsigned short ethL[64 * ETH_STRIDE];
  __shared__ unsigned short Wbuf[256 * 32];
  __shared__ float wsum[4][64];
  const int tid  = threadIdx.x;
  const int lane = tid & 63;
  const int w    = tid >> 6;
  const int quad = lane >> 4;
  const int l15  = lane & 15;
  const int m0   = (blockIdx.x >> 2) * 64;
  const int d0   = (blockIdx.x & 3) * 256;
  const int erow = tid >> 2, eunit = tid & 3;
  const float* esrc = eth + (size_t)(m0 + erow) * DDIM + eunit * 8;
  const int wr = lane >> 2, wu = lane & 3;
  float4v er0 = *(const float4v*)(esrc);
  float4v er1 = *(const float4v*)(esrc + 4);
  float4v acc[4][4];
#pragma unroll
  for (int ct = 0; ct < 4; ++ct)
#pragma unroll
    for (int rt = 0; rt < 4; ++rt)
      acc[ct][rt] = (float4v){0.f, 0.f, 0.f, 0.f};
  for (int ek = 0; ek < 32; ++ek) {
    const int e0 = ek * 32;
    __syncthreads();
    {
      uint4v pk;
      pk.x = pk2(er0.x, er0.y); pk.y = pk2(er0.z, er0.w);
      pk.z = pk2(er1.x, er1.y); pk.w = pk2(er1.z, er1.w);
      *(uint4v*)&ethL[erow * ETH_STRIDE + eunit * 8] = pk;
    }
#pragma unroll
    for (int j = 0; j < 4; ++j) {
      int r  = (w * 4 + j) * 16 + wr;
      int ug = wu ^ ((r >> 1) & 3);
      const unsigned short* gp = Wb + (size_t)(d0 + r) * DDIM + e0 + ug * 8;
      unsigned short* lp = &Wbuf[(w * 4 + j) * 512 + lane * 8];
      __builtin_amdgcn_global_load_lds(
          (const __attribute__((address_space(1))) unsigned int*)gp,
          (__attribute__((address_space(3))) unsigned int*)lp, 16, 0, 0);
    }
    __syncthreads();
    short8 aF[4], bF[4];
#pragma unroll
    for (int rt = 0; rt < 4; ++rt)
      aF[rt] = *(const short8*)&ethL[(rt * 16 + l15) * ETH_STRIDE + quad * 8];
#pragma unroll
    for (int ct = 0; ct < 4; ++ct) {
      int dl = w * 64 + ct * 16 + l15;
      int pu = quad ^ ((dl >> 1) & 3);
      bF[ct] = *(const short8*)&Wbuf[dl * 32 + pu * 8];
    }
    if (ek < 31) {
      const float* s = esrc + (e0 + 32);
      er0 = *(const float4v*)(s);
      er1 = *(const float4v*)(s + 4);
    }
#pragma unroll
    for (int ct = 0; ct < 4; ++ct)
#pragma unroll
      for (int rt = 0; rt < 4; ++rt)
        acc[ct][rt] = __builtin_amdgcn_mfma_f32_16x16x32_bf16(aF[rt], bF[ct], acc[ct][rt], 0, 0, 0);
  }
  float p[16];
#pragma unroll
  for (int j = 0; j < 16; ++j) p[j] = 0.f;
#pragma unroll
  for (int ct = 0; ct < 4; ++ct) {
    int col = d0 + w * 64 + ct * 16 + l15;
#pragma unroll
    for (int rt = 0; rt < 4; ++rt) {
      const float* ep = elg + (size_t)(m0 + rt * 16 + quad * 4) * DDIM + col;
#pragma unroll
      for (int i = 0; i < 4; ++i)
        p[rt * 4 + i] += acc[ct][rt][i] * ep[(size_t)i * DDIM];
    }
  }
#pragma unroll
  for (int off = 1; off < 16; off <<= 1)
#pragma unroll
    for (int j = 0; j < 16; ++j)
      p[j] += __shfl_xor(p[j], off);
  if (l15 == 0) {
#pragma unroll
    for (int rt = 0; rt < 4; ++rt)
#pragma unroll
      for (int i = 0; i < 4; ++i)
        wsum[w][rt * 16 + quad * 4 + i] = p[rt * 4 + i];
  }
  __syncthreads();
  if (tid < 64) {
    float s = wsum[0][tid] + wsum[1][tid] + wsum[2][tid] + wsum[3][tid];
    atomicAdd(&out[m0 + tid], s);
  }
}

extern "C" void kernel_launch(void* const* d_in, const int* in_sizes, int n_in,
                              void* d_out, int out_size, void* d_ws, size_t ws_size,
                              hipStream_t stream) {
  (void)in_sizes; (void)n_in;
  const float* elg = (const float*)d_in[0];
  const float* eth = (const float*)d_in[1];
  const float* W   = (const float*)d_in[2];
  float* out = (float*)d_out;
  unsigned short* Wb   = (unsigned short*)d_ws;                      // 2 MB
  unsigned short* ethB = (unsigned short*)((char*)d_ws + (2 << 20)); // 64 MB

  const size_t need = (2ull << 20) + (64ull << 20);
  hipMemsetAsync(d_out, 0, (size_t)out_size * sizeof(float), stream);
  if (ws_size >= need) {
    convert_all<<<dim3(512 + 16384), dim3(256), 0, stream>>>(W, eth, Wb, ethB);
    bilinear_bf16<<<dim3(2048), dim3(256), 0, stream>>>(elg, ethB, Wb, out);
  } else {
    convert_w<<<dim3(512), dim3(256), 0, stream>>>(W, Wb);
    bilinear_fp32eth<<<dim3(2048), dim3(256), 0, stream>>>(elg, eth, Wb, out);
  }
}